// Round 4
// baseline (44.217 us; speedup 1.0000x reference)
//
#include <hip/hip_runtime.h>
#include <hip/hip_cooperative_groups.h>

namespace cg = cooperative_groups;

// MutexLoss: 8 images x 32 boxes; 100 fragment pts/box; 100 boundary pts/box.
// loss = mean_img( sum_{k,f,j!=k} [frag(k,f) inside box j] * min_b d2(frag(k,f), bnd(j,b)) / 3168 )
//
// Single cooperative kernel:
//  - 256 blocks (one per (img, k)); analytic nearest-boundary-sample min
//    (boundary samples are uniformly spaced on 4 edges -> argmin per edge is
//    round(normalized coord * 24), reconstructed exactly as the reference:
//    s*wh + origin with s[24]=1.0). Block partial -> d_ws[blk].
//  - __threadfence + grid.sync() makes partials device-visible (cross-XCD),
//    then block 0's first wave reduces 256 partials and writes out[0].

#define KB   32
#define FPn  100

__device__ __forceinline__ float s25v(int j) { return (j == 24) ? 1.0f : (float)j * (1.0f / 24.0f); }
__device__ __forceinline__ float s10v(int j) { return (j == 9) ? 1.0f : (float)j * (1.0f / 9.0f); }

__global__ __launch_bounds__(128) void mutex_fused_kernel(const float* __restrict__ boxes,
                                                          float* __restrict__ partial,
                                                          float* __restrict__ out) {
    const int blk = blockIdx.x;      // 0..255
    const int img = blk >> 5;        // image index
    const int k   = blk & 31;        // box index within image
    const int tid = threadIdx.x;     // 128 threads; lanes 0..99 hold frag pts

    __shared__ float4 sbox[KB];      // x0, y0, x1, y1 (extents)
    __shared__ float2 sinv[KB];      // 24/w, 24/h
    __shared__ float  wsum[2];

    if (tid < KB) {
        const float4 b = reinterpret_cast<const float4*>(boxes)[img * KB + tid];
        const float hx = b.z * 0.5f, hy = b.w * 0.5f;
        const float x0 = b.x - hx, y0 = b.y - hy;
        const float x1 = b.x + hx, y1 = b.y + hy;
        sbox[tid] = make_float4(x0, y0, x1, y1);
        sinv[tid] = make_float2(24.0f / (x1 - x0), 24.0f / (y1 - y0));
    }
    __syncthreads();

    // Fragment point of box k owned by this lane: frag = s10 * wh + origin.
    const bool active = (tid < FPn);
    const float4 Bk = sbox[k];
    const float wk = Bk.z - Bk.x, hk = Bk.w - Bk.y;
    const int fi = tid / 10, fj = tid - fi * 10;
    const float fx = s10v(fi) * wk + Bk.x;
    const float fy = s10v(fj) * hk + Bk.y;

    float sum = 0.0f;
#pragma unroll
    for (int j = 0; j < KB; ++j) {
        const float4 B = sbox[j];        // uniform address -> broadcast
        const float2 I = sinv[j];
        const float w = B.z - B.x, h = B.w - B.y;

        // Vertical edges (x in {x0, x1}, y sampled at 25 points):
        int jy = __float2int_rn((fy - B.y) * I.y);
        jy = max(0, min(24, jy));
        const float sy  = s25v(jy) * h + B.y;    // reference's exact sample position
        const float dyv = fy - sy;
        const float dxl = fx - B.x, dxr = fx - B.z;
        const float d2a = fminf(dxl * dxl, dxr * dxr) + dyv * dyv;

        // Horizontal edges (y in {y0, y1}, x sampled at 25 points):
        int jx = __float2int_rn((fx - B.x) * I.x);
        jx = max(0, min(24, jx));
        const float sx  = s25v(jx) * w + B.x;
        const float dxh = fx - sx;
        const float dyb = fy - B.y, dyt = fy - B.w;
        const float d2b = fminf(dyb * dyb, dyt * dyt) + dxh * dxh;

        const float d2 = fminf(d2a, d2b);

        // Inclusive containment ((diff >= 0).sum == 4), excluding j == k.
        const bool in = active && (j != k) &&
                        (fx >= B.x) && (fy >= B.y) && (fx <= B.z) && (fy <= B.w);
        sum += in ? d2 : 0.0f;
    }

    // Block reduction: wave shuffle then 2-wave combine; plain store.
    for (int o = 32; o > 0; o >>= 1) sum += __shfl_down(sum, o);
    if ((tid & 63) == 0) wsum[tid >> 6] = sum;
    __syncthreads();
    if (tid == 0) partial[blk] = wsum[0] + wsum[1];
    __threadfence();                  // make partial visible at device scope

    cg::this_grid().sync();

    if (blk == 0 && tid < 64) {       // one wave reduces 256 partials
        const float4 v = reinterpret_cast<const float4*>(partial)[tid];
        float s = (v.x + v.y) + (v.z + v.w);
        for (int o = 32; o > 0; o >>= 1) s += __shfl_down(s, o);
        if (tid == 0) out[0] = s * (1.0f / 25344.0f);  // /(K*FP-K)=3168, /8 images
    }
}

extern "C" void kernel_launch(void* const* d_in, const int* in_sizes, int n_in,
                              void* d_out, int out_size, void* d_ws, size_t ws_size,
                              hipStream_t stream) {
    const float* boxes = (const float*)d_in[0];   // (256, 4) centers: xc, yc, w, h
    float* out = (float*)d_out;                   // scalar f32
    float* partial = (float*)d_ws;                // 256 floats of scratch
    (void)ws_size; (void)in_sizes; (void)n_in; (void)out_size;

    void* args[] = { (void*)&boxes, (void*)&partial, (void*)&out };
    hipLaunchCooperativeKernel((const void*)mutex_fused_kernel,
                               dim3(256), dim3(128), args, 0, stream);
}

// Round 5
// 14.184 us; speedup vs baseline: 3.1174x; 3.1174x over previous
//
#include <hip/hip_runtime.h>

// MutexLoss: 8 images x 32 boxes; 100 fragment pts/box; 100 boundary pts/box.
// loss = mean_img( sum_{k,f,j!=k} [frag(k,f) inside box j] * min_b d2(frag(k,f), bnd(j,b)) / 3168 )
//
// Structure (R3, proven 14.0 us; cooperative grid.sync was 44 us — reverted):
//  - kernel 1: 256 blocks (one per (img, k)); analytic nearest-boundary-sample
//    min (boundary samples are uniformly spaced on 4 edges -> per-edge argmin is
//    round(normalized coord * 24), reconstructed exactly as the reference:
//    s*wh + origin, s[24]=1.0). Block partial -> d_ws[blk], plain store.
//  - kernel 2: one 64-lane wave reduces the 256 partials; kernel boundary on
//    the stream provides cross-XCD visibility. out[0] overwritten each call.
//  - NEW: wave-uniform skip of j when boxes k,j are disjoint (containment
//    impossible -> iteration contributes exactly 0; result bit-identical).

#define KB   32
#define FPn  100

__device__ __forceinline__ float s25v(int j) { return (j == 24) ? 1.0f : (float)j * (1.0f / 24.0f); }
__device__ __forceinline__ float s10v(int j) { return (j == 9) ? 1.0f : (float)j * (1.0f / 9.0f); }

__global__ __launch_bounds__(128) void mutex_partial_kernel(const float* __restrict__ boxes,
                                                            float* __restrict__ partial) {
    const int blk = blockIdx.x;      // 0..255
    const int img = blk >> 5;        // image index
    const int k   = blk & 31;        // box index within image
    const int tid = threadIdx.x;     // 128 threads; lanes 0..99 hold frag pts

    __shared__ float4 sbox[KB];      // x0, y0, x1, y1 (extents)
    __shared__ float2 sinv[KB];      // 24/w, 24/h
    __shared__ float  wsum[2];

    if (tid < KB) {
        const float4 b = reinterpret_cast<const float4*>(boxes)[img * KB + tid];
        const float hx = b.z * 0.5f, hy = b.w * 0.5f;
        const float x0 = b.x - hx, y0 = b.y - hy;
        const float x1 = b.x + hx, y1 = b.y + hy;
        sbox[tid] = make_float4(x0, y0, x1, y1);
        sinv[tid] = make_float2(24.0f / (x1 - x0), 24.0f / (y1 - y0));
    }
    __syncthreads();

    // Fragment point of box k owned by this lane: frag = s10 * wh + origin.
    const bool active = (tid < FPn);
    const float4 Bk = sbox[k];
    const float wk = Bk.z - Bk.x, hk = Bk.w - Bk.y;
    const int fi = tid / 10, fj = tid - fi * 10;
    const float fx = s10v(fi) * wk + Bk.x;
    const float fy = s10v(fj) * hk + Bk.y;

    float sum = 0.0f;
#pragma unroll
    for (int j = 0; j < KB; ++j) {
        const float4 B = sbox[j];        // uniform address -> broadcast
        // Wave-uniform skip: if boxes k and j are disjoint (inclusive), no
        // frag point of k can be inside j -> iteration adds exactly 0.
        if (j == k || Bk.z < B.x || B.z < Bk.x || Bk.w < B.y || B.w < Bk.y) continue;

        const float2 I = sinv[j];
        const float w = B.z - B.x, h = B.w - B.y;

        // Vertical edges (x in {x0, x1}, y sampled at 25 points):
        int jy = __float2int_rn((fy - B.y) * I.y);
        jy = max(0, min(24, jy));
        const float sy  = s25v(jy) * h + B.y;    // reference's exact sample position
        const float dyv = fy - sy;
        const float dxl = fx - B.x, dxr = fx - B.z;
        const float d2a = fminf(dxl * dxl, dxr * dxr) + dyv * dyv;

        // Horizontal edges (y in {y0, y1}, x sampled at 25 points):
        int jx = __float2int_rn((fx - B.x) * I.x);
        jx = max(0, min(24, jx));
        const float sx  = s25v(jx) * w + B.x;
        const float dxh = fx - sx;
        const float dyb = fy - B.y, dyt = fy - B.w;
        const float d2b = fminf(dyb * dyb, dyt * dyt) + dxh * dxh;

        const float d2 = fminf(d2a, d2b);

        // Inclusive containment ((diff >= 0).sum == 4).
        const bool in = active &&
                        (fx >= B.x) && (fy >= B.y) && (fx <= B.z) && (fy <= B.w);
        sum += in ? d2 : 0.0f;
    }

    // Block reduction: wave shuffle then 2-wave combine; plain store, no atomic.
    for (int o = 32; o > 0; o >>= 1) sum += __shfl_down(sum, o);
    if ((tid & 63) == 0) wsum[tid >> 6] = sum;
    __syncthreads();
    if (tid == 0) partial[blk] = wsum[0] + wsum[1];
}

__global__ __launch_bounds__(64) void mutex_reduce_kernel(const float* __restrict__ partial,
                                                          float* __restrict__ out) {
    const int lane = threadIdx.x;    // single wave: 64 lanes x float4 = 256 partials
    const float4 v = reinterpret_cast<const float4*>(partial)[lane];
    float s = (v.x + v.y) + (v.z + v.w);
    for (int o = 32; o > 0; o >>= 1) s += __shfl_down(s, o);
    if (lane == 0) out[0] = s * (1.0f / 25344.0f);  // /(K*FP-K)=3168, /8 images
}

extern "C" void kernel_launch(void* const* d_in, const int* in_sizes, int n_in,
                              void* d_out, int out_size, void* d_ws, size_t ws_size,
                              hipStream_t stream) {
    const float* boxes = (const float*)d_in[0];   // (256, 4) centers: xc, yc, w, h
    float* out = (float*)d_out;                   // scalar f32
    float* partial = (float*)d_ws;                // 256 floats of scratch
    (void)ws_size; (void)in_sizes; (void)n_in; (void)out_size;

    mutex_partial_kernel<<<256, 128, 0, stream>>>(boxes, partial);
    mutex_reduce_kernel<<<1, 64, 0, stream>>>(partial, out);
}